// Round 5
// baseline (634.786 us; speedup 1.0000x reference)
//
#include <hip/hip_runtime.h>
#include <cstdint>
#include <cstddef>

// GraphRec forward, 5 launches: setup, engine (all row-MLPs + fused att
// scores, MFMA), stats (softmax column max/invZ), agg (hiI+zj+ho+sS score),
// tail (sS softmax + hiS + um-MLP + final rating).
// Hidden/engine outputs live in permuted position space korig(p)=(p&3)*16+(p>>2)
// (baked into pre-transposed weights); consumers read col `lane` at position
// IDX16(lane).

#define GB 512
#define GN 30
#define GD 64
#define IDX16(l) ((((l) & 15) << 2) | ((l) >> 4))

typedef unsigned short u16;
typedef __attribute__((ext_vector_type(8))) short short8v;  // 8 bf16
typedef __attribute__((ext_vector_type(4))) float f32x4;

__device__ __forceinline__ u16 f2bf(float x) {
  union { float f; uint32_t u; } c; c.f = x;
  uint32_t r = c.u + 0x7fffu + ((c.u >> 16) & 1u);
  return (u16)(r >> 16);
}
__device__ __forceinline__ float bf2f(u16 b) {
  union { float f; uint32_t u; } c; c.u = ((uint32_t)b) << 16; return c.f;
}
__device__ __forceinline__ float wave_sum(float v) {
#pragma unroll
  for (int off = 32; off >= 1; off >>= 1) v += __shfl_xor(v, off, 64);
  return v;
}
__device__ __forceinline__ float wave_max(float v) {
#pragma unroll
  for (int off = 32; off >= 1; off >>= 1) v = fmaxf(v, __shfl_xor(v, off, 64));
  return v;
}

// =============== 1. setup: weight transpose/permute + rowlin precomputes ===============
__global__ __launch_bounds__(256) void k_setup(
    const float* __restrict__ gvW1, const float* __restrict__ gvW2, const float* __restrict__ gvW3,
    const float* __restrict__ guW1, const float* __restrict__ guW2, const float* __restrict__ guW3,
    const float* __restrict__ umW1, const float* __restrict__ umW2, const float* __restrict__ umW3,
    const float* __restrict__ aOW1, const float* __restrict__ aIW1, const float* __restrict__ aiW1,
    const float* __restrict__ aSW1,
    const float* __restrict__ E_u, const float* __restrict__ E_i,
    const int* __restrict__ nodes_u, const int* __restrict__ nodes_i, const int* __restrict__ u_users,
    u16* gv1t, u16* gv2t, u16* gv3t, u16* gu1t, u16* gu2t, u16* gu3t,
    u16* um1t, u16* um2t, u16* um3t, u16* aOt, u16* aIt, u16* ait,
    float* piWI, float* piWS, float* qjWi, float* poW) {
  __shared__ float ws[64 * 64];
  int blk = blockIdx.x, t = threadIdx.x;
  if (blk < 240) {  // weight prep: 61440 elements
    int o = blk * 256 + t;
    const float* src; u16* dst; int kind;  // 0: K=128 plain; 1: K=64 permuted; 2: att bottom-half permuted
    if      (o < 8192)  {            src = gvW1; dst = gv1t; kind = 0; }
    else if (o < 12288) { o -= 8192;  src = gvW2; dst = gv2t; kind = 1; }
    else if (o < 16384) { o -= 12288; src = gvW3; dst = gv3t; kind = 1; }
    else if (o < 20480) { o -= 16384; src = aOW1; dst = aOt;  kind = 2; }
    else if (o < 28672) { o -= 20480; src = guW1; dst = gu1t; kind = 0; }
    else if (o < 32768) { o -= 28672; src = guW2; dst = gu2t; kind = 1; }
    else if (o < 36864) { o -= 32768; src = guW3; dst = gu3t; kind = 1; }
    else if (o < 40960) { o -= 36864; src = aIW1; dst = aIt;  kind = 2; }
    else if (o < 45056) { o -= 40960; src = aiW1; dst = ait;  kind = 2; }
    else if (o < 53248) { o -= 45056; src = umW1; dst = um1t; kind = 0; }
    else if (o < 57344) { o -= 53248; src = umW2; dst = um2t; kind = 1; }
    else                { o -= 57344; src = umW3; dst = um3t; kind = 1; }
    if (kind == 0) { int n = o >> 7, k = o & 127; dst[n * 128 + k] = f2bf(src[(size_t)k * 64 + n]); }
    else { int n = o >> 6, p = o & 63; int k = ((p & 3) << 4) | (p >> 2); if (kind == 2) k += 64;
           dst[n * 64 + p] = f2bf(src[(size_t)k * 64 + n]); }
    return;
  }
  // rowlin: out[r] = tab[idx[r]] @ W_top64
  int rb = blk - 240;
  const float* tab; const int* idx; const float* W; float* out; int base;
  if (rb < 16)      { tab = E_u; idx = nodes_u; W = aIW1; out = piWI; base = rb * 32; }
  else if (rb < 32) { tab = E_u; idx = nodes_u; W = aSW1; out = piWS; base = (rb - 16) * 32; }
  else if (rb < 48) { tab = E_i; idx = nodes_i; W = aiW1; out = qjWi; base = (rb - 32) * 32; }
  else              { tab = E_u; idx = u_users; W = aOW1; out = poW;  base = (rb - 48) * 32; }
  for (int i = t; i < 4096; i += 256) ws[i] = W[i];
  __syncthreads();
  int lane = t & 63, wave = t >> 6;
  int b0 = base + wave * 8;
  const float* p[8]; float acc[8];
#pragma unroll
  for (int r = 0; r < 8; r++) {
    p[r] = tab + (size_t)__builtin_amdgcn_readfirstlane(idx[b0 + r]) * 64;
    acc[r] = 0.f;
  }
#pragma unroll 8
  for (int k = 0; k < 64; k++) {
    float w = ws[k * 64 + lane];
#pragma unroll
    for (int r = 0; r < 8; r++) acc[r] = fmaf(p[r][k], w, acc[r]);
  }
#pragma unroll
  for (int r = 0; r < 8; r++) out[(size_t)(b0 + r) * 64 + lane] = acc[r];
}

// =============== 2. engine: all row-MLPs + fused att scores ===============
__global__ __launch_bounds__(256, 2) void k_engine(
    const float* __restrict__ E_i, const float* __restrict__ E_r, const float* __restrict__ E_u,
    const int* __restrict__ uu_items, const int* __restrict__ uu_items_r,
    const int* __restrict__ u_items, const int* __restrict__ u_items_r,
    const int* __restrict__ i_users, const int* __restrict__ i_users_r,
    const u16* __restrict__ gv1t, const u16* __restrict__ gv2t, const u16* __restrict__ gv3t,
    const u16* __restrict__ gu1t, const u16* __restrict__ gu2t, const u16* __restrict__ gu3t,
    const float* __restrict__ gvb1, const float* __restrict__ gvb2, const float* __restrict__ gvb3,
    const float* __restrict__ gub1, const float* __restrict__ gub2, const float* __restrict__ gub3,
    const u16* __restrict__ aOt, const u16* __restrict__ aIt, const u16* __restrict__ ait,
    const float* __restrict__ aOb1, const float* __restrict__ aIb1, const float* __restrict__ aib1,
    const float* __restrict__ aOW2, const float* __restrict__ aIW2, const float* __restrict__ aiW2,
    const float* __restrict__ aOb2, const float* __restrict__ aIb2, const float* __restrict__ aib2,
    const float* __restrict__ poW, const float* __restrict__ piWI, const float* __restrict__ qjWi,
    u16* __restrict__ xoa_bf, u16* __restrict__ xia_bf, u16* __restrict__ fjt_bf,
    float* __restrict__ sOT, float* __restrict__ sIT, float* __restrict__ siT) {
  __shared__ __align__(16) u16 xs[64 * 136], w1s[64 * 136], was[64 * 72], hs[64 * 72];
  __shared__ float b1s[64], b2s[64], b3s[64], ab1s[64], aw2s[64];
  int t = threadIdx.x, blk = blockIdx.x;
  const float *tabA, *tabB, *selfW, *b1, *b2, *b3, *ab1, *aW2, *ab2p;
  const int *idxA, *idxB; const u16 *w1t, *w2t, *w3t, *att;
  u16* outB; float* sT; int tile0, modeNN;
  if (blk < 480) {
    tabA = E_i; idxA = uu_items; tabB = E_r; idxB = uu_items_r;
    w1t = gv1t; w2t = gv2t; w3t = gv3t; b1 = gvb1; b2 = gvb2; b3 = gvb3;
    att = aOt; ab1 = aOb1; aW2 = aOW2; ab2p = aOb2; selfW = poW;
    outB = xoa_bf; sT = sOT; tile0 = blk * 15; modeNN = 1;
  } else if (blk < 496) {
    int lb = blk - 480;
    tabA = E_i; idxA = u_items; tabB = E_r; idxB = u_items_r;
    w1t = gv1t; w2t = gv2t; w3t = gv3t; b1 = gvb1; b2 = gvb2; b3 = gvb3;
    att = aIt; ab1 = aIb1; aW2 = aIW2; ab2p = aIb2; selfW = piWI;
    outB = xia_bf; sT = sIT; tile0 = lb * 15; modeNN = 0;
  } else {
    int lb = blk - 496;
    tabA = E_u; idxA = i_users; tabB = E_r; idxB = i_users_r;
    w1t = gu1t; w2t = gu2t; w3t = gu3t; b1 = gub1; b2 = gub2; b3 = gub3;
    att = ait; ab1 = aib1; aW2 = aiW2; ab2p = aib2; selfW = qjWi;
    outB = fjt_bf; sT = siT; tile0 = lb * 15; modeNN = 0;
  }
  const int nt = 15;
  for (int i = t; i < 64 * 16; i += 256) { int n = i >> 4, j = i & 15;
    ((uint4*)(w1s + n * 136))[j] = ((const uint4*)(w1t + n * 128))[j]; }
  for (int i = t; i < 64 * 8; i += 256) { int n = i >> 3, j = i & 7;
    ((uint4*)(was + n * 72))[j] = ((const uint4*)(att + n * 64))[j]; }
  if (t < 64) { b1s[t] = b1[t]; b2s[t] = b2[t]; b3s[t] = b3[t];
                ab1s[t] = ab1[t]; aw2s[t] = aW2[t]; }
  __syncthreads();   // staged weights ready; all below is wave-private
  const int lane = t & 63, wave = t >> 6, m = lane & 15, quad = lane >> 4;
  const int lr = t >> 2, q = t & 3;
  // layer-2/3 B-fragments in registers (position space = permuted prep)
  short8v w2f[8], w3f[8];
#pragma unroll
  for (int c = 0; c < 4; c++)
#pragma unroll
    for (int kk = 0; kk < 2; kk++) {
      int off = (c * 16 + m) * 64 + kk * 32 + quad * 8;
      w2f[c * 2 + kk] = *(const short8v*)(w2t + off);
      w3f[c * 2 + kk] = *(const short8v*)(w3t + off);
    }
  const float ab2v = ab2p[0];
  const f32x4 zz = {0.f, 0.f, 0.f, 0.f};
  const float* srcTab = (q < 2) ? tabA : tabB;
  const int qoff = (q < 2) ? q * 32 : (q - 2) * 32;
  int idxcur;
  { int row0 = tile0 * 64 + lr; idxcur = (q < 2) ? idxA[row0] : idxB[row0]; }
  for (int it = 0; it < nt; it++) {
    int base = (tile0 + it) * 64;
    // gather this tile's rows (batched loads), prefetch next tile's index
    {
      const float4* s4 = (const float4*)(srcTab + (size_t)idxcur * 64 + qoff);
      float4 v[8];
#pragma unroll
      for (int h = 0; h < 8; h++) v[h] = s4[h];
      if (it + 1 < nt) {
        int rown = base + 64 + lr;
        idxcur = (q < 2) ? idxA[rown] : idxB[rown];
      }
      u16* dst = xs + lr * 136 + q * 32;
#pragma unroll
      for (int h = 0; h < 8; h++) { ushort4 u;
        u.x = f2bf(v[h].x); u.y = f2bf(v[h].y); u.z = f2bf(v[h].z); u.w = f2bf(v[h].w);
        *(ushort4*)(dst + h * 4) = u; }
    }
    // layer 1 (K=128)
    f32x4 cc[4];
#pragma unroll
    for (int c = 0; c < 4; c++) cc[c] = zz;
#pragma unroll
    for (int kk = 0; kk < 4; kk++) {
      short8v av = *(const short8v*)(xs + (wave * 16 + m) * 136 + kk * 32 + quad * 8);
#pragma unroll
      for (int c = 0; c < 4; c++) {
        short8v bv = *(const short8v*)(w1s + (c * 16 + m) * 136 + kk * 32 + quad * 8);
        cc[c] = __builtin_amdgcn_mfma_f32_16x16x32_bf16(av, bv, cc[c], 0, 0, 0);
      }
    }
#pragma unroll
    for (int r = 0; r < 4; r++) { ushort4 u;
      u.x = f2bf(fmaxf(cc[0][r] + b1s[m], 0.f));
      u.y = f2bf(fmaxf(cc[1][r] + b1s[16 + m], 0.f));
      u.z = f2bf(fmaxf(cc[2][r] + b1s[32 + m], 0.f));
      u.w = f2bf(fmaxf(cc[3][r] + b1s[48 + m], 0.f));
      *(ushort4*)(hs + (wave * 16 + quad * 4 + r) * 72 + m * 4) = u; }
    // layer 2
#pragma unroll
    for (int c = 0; c < 4; c++) cc[c] = zz;
#pragma unroll
    for (int kk = 0; kk < 2; kk++) {
      short8v av = *(const short8v*)(hs + (wave * 16 + m) * 72 + kk * 32 + quad * 8);
#pragma unroll
      for (int c = 0; c < 4; c++)
        cc[c] = __builtin_amdgcn_mfma_f32_16x16x32_bf16(av, w2f[c * 2 + kk], cc[c], 0, 0, 0);
    }
#pragma unroll
    for (int r = 0; r < 4; r++) { ushort4 u;
      u.x = f2bf(fmaxf(cc[0][r] + b2s[m], 0.f));
      u.y = f2bf(fmaxf(cc[1][r] + b2s[16 + m], 0.f));
      u.z = f2bf(fmaxf(cc[2][r] + b2s[32 + m], 0.f));
      u.w = f2bf(fmaxf(cc[3][r] + b2s[48 + m], 0.f));
      *(ushort4*)(hs + (wave * 16 + quad * 4 + r) * 72 + m * 4) = u; }
    // layer 3 (no relu)
    f32x4 c3[4];
#pragma unroll
    for (int c = 0; c < 4; c++) c3[c] = zz;
#pragma unroll
    for (int kk = 0; kk < 2; kk++) {
      short8v av = *(const short8v*)(hs + (wave * 16 + m) * 72 + kk * 32 + quad * 8);
#pragma unroll
      for (int c = 0; c < 4; c++)
        c3[c] = __builtin_amdgcn_mfma_f32_16x16x32_bf16(av, w3f[c * 2 + kk], c3[c], 0, 0, 0);
    }
#pragma unroll
    for (int r = 0; r < 4; r++) { ushort4 u;
      u.x = f2bf(c3[0][r] + b3s[m]);
      u.y = f2bf(c3[1][r] + b3s[16 + m]);
      u.z = f2bf(c3[2][r] + b3s[32 + m]);
      u.w = f2bf(c3[3][r] + b3s[48 + m]);
      *(ushort4*)(hs + (wave * 16 + quad * 4 + r) * 72 + m * 4) = u; }
    // coalesced bf16 store (permuted positions; consumers use IDX16)
#pragma unroll
    for (int c2 = 0; c2 < 2; c2++) {
      int chunk = lane * 2 + c2; int row = chunk >> 3, k8 = chunk & 7;
      *(uint4*)(outB + ((size_t)(base + wave * 16 + row)) * 64 + k8 * 8) =
          *(const uint4*)(hs + (wave * 16 + row) * 72 + k8 * 8);
    }
    // fused att score
    f32x4 c4[4];
#pragma unroll
    for (int c = 0; c < 4; c++) c4[c] = zz;
#pragma unroll
    for (int kk = 0; kk < 2; kk++) {
      short8v av = *(const short8v*)(hs + (wave * 16 + m) * 72 + kk * 32 + quad * 8);
#pragma unroll
      for (int c = 0; c < 4; c++) {
        short8v bv = *(const short8v*)(was + (c * 16 + m) * 72 + kk * 32 + quad * 8);
        c4[c] = __builtin_amdgcn_mfma_f32_16x16x32_bf16(av, bv, c4[c], 0, 0, 0);
      }
    }
    float part[4];
#pragma unroll
    for (int r = 0; r < 4; r++) {
      int gRow = base + wave * 16 + quad * 4 + r;
      int sidx = modeNN ? ((gRow / (GN * GN)) * GN + gRow % GN) : (gRow / GN);
      const float* pw = selfW + (size_t)sidx * 64;
      float s = 0.f;
#pragma unroll
      for (int c = 0; c < 4; c++) {
        int col = c * 16 + m;
        s += fmaxf(c4[c][r] + pw[col] + ab1s[col], 0.f) * aw2s[col];
      }
      part[r] = s;
    }
#pragma unroll
    for (int r = 0; r < 4; r++) {
      float v = part[r];
      v += __shfl_xor(v, 1, 64); v += __shfl_xor(v, 2, 64);
      v += __shfl_xor(v, 4, 64); v += __shfl_xor(v, 8, 64);
      if (m == 0) {
        int gRow = base + wave * 16 + quad * 4 + r;
        int scol, sb;
        if (modeNN) { sb = gRow / (GN * GN); scol = gRow % (GN * GN); }
        else        { sb = gRow / GN;        scol = gRow % GN; }
        sT[(size_t)scol * GB + sb] = v + ab2v;
      }
    }
  }
}

// =============== 3. stats: per-column softmax max + 1/Z ===============
// cols: 0..29 sIT, 30..59 siT, 60..959 sOT (n1*30+n2). stats[2c]=M, [2c+1]=1/Z.
__global__ __launch_bounds__(256) void k_stats(
    const float* __restrict__ sIT, const float* __restrict__ siT, const float* __restrict__ sOT,
    float* __restrict__ stats) {
  int c = blockIdx.x, t = threadIdx.x;
  const float* p;
  if (c < 30)      p = sIT + (size_t)c * GB;
  else if (c < 60) p = siT + (size_t)(c - 30) * GB;
  else             p = sOT + (size_t)(c - 60) * GB;
  int lane = t & 63, wave = t >> 6;
  float v0 = p[t], v1 = p[t + 256];
  float mx = wave_max(fmaxf(v0, v1));
  __shared__ float rm[4], rs[4];
  if (lane == 0) rm[wave] = mx;
  __syncthreads();
  float M4 = fmaxf(fmaxf(rm[0], rm[1]), fmaxf(rm[2], rm[3]));
  float sm = wave_sum(__expf(v0 - M4) + __expf(v1 - M4));
  if (lane == 0) rs[wave] = sm;
  __syncthreads();
  if (t == 0) {
    stats[2 * c] = M4;
    stats[2 * c + 1] = 1.f / (rs[0] + rs[1] + rs[2] + rs[3]);
  }
}

// =============== 4. agg: hiI, zj, ho (+fused sS score) ===============
__global__ __launch_bounds__(256) void k_agg(
    const u16* __restrict__ xia_bf, const u16* __restrict__ fjt_bf, const u16* __restrict__ xoa_bf,
    const float* __restrict__ sIT, const float* __restrict__ siT, const float* __restrict__ sOT,
    const float* __restrict__ stats,
    const float* __restrict__ linIW, const float* __restrict__ linIb,
    const float* __restrict__ ilinW, const float* __restrict__ ilinb,
    const float* __restrict__ linOW, const float* __restrict__ linOb,
    const float* __restrict__ aSW1, const float* __restrict__ aSb1,
    const float* __restrict__ aSW2, const float* __restrict__ aSb2,
    const float* __restrict__ piWS,
    float* __restrict__ hiI, float* __restrict__ zj, float* __restrict__ ho,
    float* __restrict__ sST) {
  __shared__ float ws[64 * 64];
  __shared__ float ws2[64 * 64];
  __shared__ float ts[4][64];
  int blk = blockIdx.x, t = threadIdx.x, lane = t & 63, wave = t >> 6;
  int px = IDX16(lane);
  if (blk < 64) {  // hiI (blk<32) / zj: 16 b per block, 4 per wave
    const float* W = (blk < 32) ? linIW : ilinW;
    for (int i = t; i < 4096; i += 256) ws[i] = W[i];
    __syncthreads();
    const u16* X = (blk < 32) ? xia_bf : fjt_bf;
    const float* sRaw = (blk < 32) ? sIT : siT;
    const float* st = stats + ((blk < 32) ? 0 : 60);
    const float* bias = (blk < 32) ? linIb : ilinb;
    float* outp = (blk < 32) ? hiI : zj;
    int bbase = (blk & 31) * 16 + wave * 4;
    for (int bs = 0; bs < 4; bs++) {
      int b = bbase + bs;
      float acc = 0.f;
#pragma unroll 6
      for (int n = 0; n < GN; n++) {
        float al = __expf(sRaw[(size_t)n * GB + b] - st[2 * n]) * st[2 * n + 1];
        acc = fmaf(al, bf2f(X[((size_t)b * GN + n) * 64 + px]), acc);
      }
      ts[wave][lane] = acc;   // wave-private, program order
      float o = bias[lane];
#pragma unroll 8
      for (int k = 0; k < 64; k++) o = fmaf(ts[wave][k], ws[k * 64 + lane], o);
      outp[(size_t)b * 64 + lane] = fmaxf(o, 0.f);
    }
    return;
  }
  // ho blocks: 8 gids per block (2 per wave), fused att_S score
  for (int i = t; i < 4096; i += 256) { ws[i] = linOW[i]; ws2[i] = aSW1[64 * 64 + i]; }
  __syncthreads();
  const float* stO = stats + 2 * 60;
  float aSb2v = aSb2[0];
  int gbase = (blk - 64) * 8 + wave * 2;
  for (int g2 = 0; g2 < 2; g2++) {
    int gid = gbase + g2;
    int b_ = gid / GN, n2 = gid - b_ * GN;
    float acc = 0.f;
#pragma unroll 6
    for (int n1 = 0; n1 < GN; n1++) {
      int col = n1 * GN + n2;
      float al = __expf(sOT[(size_t)col * GB + b_] - stO[2 * col]) * stO[2 * col + 1];
      acc = fmaf(al, bf2f(xoa_bf[(((size_t)b_ * GN + n1) * GN + n2) * 64 + px]), acc);
    }
    ts[wave][lane] = acc;
    float o = linOb[lane];
#pragma unroll 8
    for (int k = 0; k < 64; k++) o = fmaf(ts[wave][k], ws[k * 64 + lane], o);
    o = fmaxf(o, 0.f);
    ho[(size_t)gid * 64 + lane] = o;
    // fused att_S score: relu(piWS[b_] + ho_row @ aSW1b + aSb1) . aSW2 + aSb2
    ts[wave][lane] = o;   // safe: all lanes finished reading ts above (lockstep)
    float h = piWS[(size_t)b_ * 64 + lane] + aSb1[lane];
#pragma unroll 8
    for (int k = 0; k < 64; k++) h = fmaf(ts[wave][k], ws2[k * 64 + lane], h);
    float v = fmaxf(h, 0.f) * aSW2[lane];
    v = wave_sum(v);
    if (lane == 0) sST[(size_t)n2 * GB + b_] = v + aSb2v;
  }
}

// =============== 5. tail: sS softmax + hiS + um-MLP3 (MFMA) + final ===============
__global__ __launch_bounds__(256) void k_tail(
    const float* __restrict__ hiI, const float* __restrict__ zj,
    const float* __restrict__ ho, const float* __restrict__ sST,
    const float* __restrict__ linOW, const float* __restrict__ linOb,
    const u16* __restrict__ um1t, const u16* __restrict__ um2t, const u16* __restrict__ um3t,
    const float* __restrict__ umb1, const float* __restrict__ umb2, const float* __restrict__ umb3,
    const float* __restrict__ gW1, const float* __restrict__ gb1,
    const float* __restrict__ gW2, const float* __restrict__ gb2,
    const float* __restrict__ gW3, const float* __restrict__ gb3,
    float* __restrict__ out) {
  __shared__ __align__(16) u16 xs[64 * 136], w1s[64 * 136], hs[64 * 72];
  __shared__ float ws[64 * 64];
  __shared__ float aM[32], aZi[32];
  __shared__ float ts[4][64];
  __shared__ float b1s[64], b2s[64], b3s[64], g1s[128];
  int t = threadIdx.x, lane = t & 63, wave = t >> 6, m = lane & 15, quad = lane >> 4;
  for (int i = t; i < 64 * 16; i += 256) { int n = i >> 4, j = i & 15;
    ((uint4*)(w1s + n * 136))[j] = ((const uint4*)(um1t + n * 128))[j]; }
  for (int i = t; i < 4096; i += 256) ws[i] = linOW[i];
  if (t < 64) { b1s[t] = umb1[t]; b2s[t] = umb2[t]; b3s[t] = umb3[t]; }
  if (t < 128) g1s[t] = gW1[t];
  // phase A: per-column softmax stats of sST (each wave 8 cols)
  for (int c8 = 0; c8 < 8; c8++) {
    int col = wave * 8 + c8;
    if (col < GN) {
      float v[8];
#pragma unroll
      for (int j = 0; j < 8; j++) v[j] = sST[(size_t)col * GB + j * 64 + lane];
      float mx = v[0];
#pragma unroll
      for (int j = 1; j < 8; j++) mx = fmaxf(mx, v[j]);
      mx = wave_max(mx);
      float z = 0.f;
#pragma unroll
      for (int j = 0; j < 8; j++) z += __expf(v[j] - mx);
      z = wave_sum(z);
      if (lane == 0) { aM[col] = mx; aZi[col] = 1.f / z; }
    }
  }
  __syncthreads();
  // phase B: hiS for this wave's 16 rows -> xs (cols 64..127); hiI -> cols 0..63
  int base = blockIdx.x * 64;
  for (int bi = 0; bi < 16; bi++) {
    int row = wave * 16 + bi, b = base + row;
    float acc = 0.f;
#pragma unroll 6
    for (int n = 0; n < GN; n++) {
      float al = __expf(sST[(size_t)n * GB + b] - aM[n]) * aZi[n];
      acc = fmaf(al, ho[((size_t)b * GN + n) * 64 + lane], acc);
    }
    ts[wave][lane] = acc;
    float o = linOb[lane];
#pragma unroll 8
    for (int k = 0; k < 64; k++) o = fmaf(ts[wave][k], ws[k * 64 + lane], o);
    xs[row * 136 + 64 + lane] = f2bf(fmaxf(o, 0.f));
    xs[row * 136 + lane] = f2bf(hiI[(size_t)b * 64 + lane]);
  }
  // phase C: um MLP3 (wave-private rows)
  short8v w2f[8], w3f[8];
#pragma unroll
  for (int c = 0; c < 4; c++)
#pragma unroll
    for (int kk = 0; kk < 2; kk++) {
      int off = (c * 16 + m) * 64 + kk * 32 + quad * 8;
      w2f[c * 2 + kk] = *(const short8v*)(um2t + off);
      w3f[c * 2 + kk] = *(const short8v*)(um3t + off);
    }
  const f32x4 zz = {0.f, 0.f, 0.f, 0.f};
  f32x4 cc[4];
#pragma unroll
  for (int c = 0; c < 4; c++) cc[c] = zz;
#pragma unroll
  for (int kk = 0; kk < 4; kk++) {
    short8v av = *(const short8v*)(xs + (wave * 16 + m) * 136 + kk * 32 + quad * 8);
#pragma unroll
    for (int c = 0; c < 4; c++) {
      short8v bv = *(const short8v*)(w1s + (c * 16 + m) * 136 + kk * 32 + quad * 8);
      cc[c] = __builtin_amdgcn_mfma_f32_16x16x32_bf16(av, bv, cc[c], 0, 0, 0);
    }
  }
#pragma unroll
  for (int r = 0; r < 4; r++) { ushort4 u;
    u.x = f2bf(fmaxf(cc[0][r] + b1s[m], 0.f));
    u.y = f2bf(fmaxf(cc[1][r] + b1s[16 + m], 0.f));
    u.z = f2bf(fmaxf(cc[2][r] + b1s[32 + m], 0.f));
    u.w = f2bf(fmaxf(cc[3][r] + b1s[48 + m], 0.f));
    *(ushort4*)(hs + (wave * 16 + quad * 4 + r) * 72 + m * 4) = u; }
#pragma unroll
  for (int c = 0; c < 4; c++) cc[c] = zz;
#pragma unroll
  for (int kk = 0; kk < 2; kk++) {
    short8v av = *(const short8v*)(hs + (wave * 16 + m) * 72 + kk * 32 + quad * 8);
#pragma unroll
    for (int c = 0; c < 4; c++)
      cc[c] = __builtin_amdgcn_mfma_f32_16x16x32_bf16(av, w2f[c * 2 + kk], cc[c], 0, 0, 0);
  }
#pragma unroll
  for (int r = 0; r < 4; r++) { ushort4 u;
    u.x = f2bf(fmaxf(cc[0][r] + b2s[m], 0.f));
    u.y = f2bf(fmaxf(cc[1][r] + b2s[16 + m], 0.f));
    u.z = f2bf(fmaxf(cc[2][r] + b2s[32 + m], 0.f));
    u.w = f2bf(fmaxf(cc[3][r] + b2s[48 + m], 0.f));
    *(ushort4*)(hs + (wave * 16 + quad * 4 + r) * 72 + m * 4) = u; }
  f32x4 c3[4];
#pragma unroll
  for (int c = 0; c < 4; c++) c3[c] = zz;
#pragma unroll
  for (int kk = 0; kk < 2; kk++) {
    short8v av = *(const short8v*)(hs + (wave * 16 + m) * 72 + kk * 32 + quad * 8);
#pragma unroll
    for (int c = 0; c < 4; c++)
      c3[c] = __builtin_amdgcn_mfma_f32_16x16x32_bf16(av, w3f[c * 2 + kk], c3[c], 0, 0, 0);
  }
#pragma unroll
  for (int r = 0; r < 4; r++) { ushort4 u;
    u.x = f2bf(c3[0][r] + b3s[m]);
    u.y = f2bf(c3[1][r] + b3s[16 + m]);
    u.z = f2bf(c3[2][r] + b3s[32 + m]);
    u.w = f2bf(c3[3][r] + b3s[48 + m]);
    *(ushort4*)(hs + (wave * 16 + quad * 4 + r) * 72 + m * 4) = u; }
  // phase D: final rating
  float gb1v = gb1[0], gb2v = gb2[0], gb3v = gb3[0], gW2v = gW2[0], gW3v = gW3[0];
  int px = IDX16(lane);
  for (int r16 = 0; r16 < 16; r16++) {
    int row = wave * 16 + r16, b = base + row;
    float v = bf2f(hs[row * 72 + px]) * g1s[lane] + zj[(size_t)b * 64 + lane] * g1s[64 + lane];
    v = wave_sum(v);
    if (lane == 0) {
      float h = fmaxf(v + gb1v, 0.f);
      h = fmaxf(h * gW2v + gb2v, 0.f);
      out[b] = h * gW3v + gb3v;
    }
  }
}

extern "C" void kernel_launch(void* const* d_in, const int* in_sizes, int n_in,
                              void* d_out, int out_size, void* d_ws, size_t ws_size,
                              hipStream_t stream) {
  const float* E_u = (const float*)d_in[0];
  const float* E_i = (const float*)d_in[1];
  const float* E_r = (const float*)d_in[2];
  const float* gvW1 = (const float*)d_in[3];  const float* gvb1 = (const float*)d_in[4];
  const float* gvW2 = (const float*)d_in[5];  const float* gvb2 = (const float*)d_in[6];
  const float* gvW3 = (const float*)d_in[7];  const float* gvb3 = (const float*)d_in[8];
  const float* umW1 = (const float*)d_in[9];  const float* umb1 = (const float*)d_in[10];
  const float* umW2 = (const float*)d_in[11]; const float* umb2 = (const float*)d_in[12];
  const float* umW3 = (const float*)d_in[13]; const float* umb3 = (const float*)d_in[14];
  const float* guW1 = (const float*)d_in[15]; const float* gub1 = (const float*)d_in[16];
  const float* guW2 = (const float*)d_in[17]; const float* gub2 = (const float*)d_in[18];
  const float* guW3 = (const float*)d_in[19]; const float* gub3 = (const float*)d_in[20];
  const float* aIW1 = (const float*)d_in[21]; const float* aIb1 = (const float*)d_in[22];
  const float* aIW2 = (const float*)d_in[23]; const float* aIb2 = (const float*)d_in[24];
  const float* aOW1 = (const float*)d_in[25]; const float* aOb1 = (const float*)d_in[26];
  const float* aOW2 = (const float*)d_in[27]; const float* aOb2 = (const float*)d_in[28];
  const float* aSW1 = (const float*)d_in[29]; const float* aSb1 = (const float*)d_in[30];
  const float* aSW2 = (const float*)d_in[31]; const float* aSb2 = (const float*)d_in[32];
  const float* aiW1 = (const float*)d_in[33]; const float* aib1 = (const float*)d_in[34];
  const float* aiW2 = (const float*)d_in[35]; const float* aib2 = (const float*)d_in[36];
  const float* linIW = (const float*)d_in[37]; const float* linIb = (const float*)d_in[38];
  const float* linOW = (const float*)d_in[39]; const float* linOb = (const float*)d_in[40];
  const float* ilinW = (const float*)d_in[41]; const float* ilinb = (const float*)d_in[42];
  const float* gW1 = (const float*)d_in[43]; const float* gb1 = (const float*)d_in[44];
  const float* gW2 = (const float*)d_in[45]; const float* gb2 = (const float*)d_in[46];
  const float* gW3 = (const float*)d_in[47]; const float* gb3 = (const float*)d_in[48];
  const int* nodes_u = (const int*)d_in[49];
  const int* nodes_i = (const int*)d_in[50];
  const int* u_items = (const int*)d_in[51];
  const int* u_users = (const int*)d_in[52];
  const int* i_users = (const int*)d_in[53];
  const int* u_items_r = (const int*)d_in[54];
  const int* uu_items = (const int*)d_in[55];
  const int* uu_items_r = (const int*)d_in[56];
  const int* i_users_r = (const int*)d_in[57];
  float* out = (float*)d_out;

  const int BN = GB * GN;        // 15360
  const int M2 = GB * GN * GN;   // 460800

  float* p = (float*)d_ws;
  float* piWI = p; p += GB * GD;
  float* piWS = p; p += GB * GD;
  float* qjWi = p; p += GB * GD;
  float* poW  = p; p += BN * GD;
  float* ho   = p; p += BN * GD;
  float* sIT  = p; p += BN;
  float* siT  = p; p += BN;
  float* sST  = p; p += BN;
  float* sOT  = p; p += M2;
  float* hiI  = p; p += GB * GD;
  float* zj   = p; p += GB * GD;
  float* stats = p; p += 2 * 1020;
  u16* q16 = (u16*)p;
  u16* gv1t = q16; q16 += 8192;
  u16* gv2t = q16; q16 += 4096;
  u16* gv3t = q16; q16 += 4096;
  u16* gu1t = q16; q16 += 8192;
  u16* gu2t = q16; q16 += 4096;
  u16* gu3t = q16; q16 += 4096;
  u16* um1t = q16; q16 += 8192;
  u16* um2t = q16; q16 += 4096;
  u16* um3t = q16; q16 += 4096;
  u16* aOt  = q16; q16 += 4096;
  u16* aIt  = q16; q16 += 4096;
  u16* ait  = q16; q16 += 4096;
  u16* xia_bf = q16; q16 += (size_t)BN * GD;
  u16* fjt_bf = q16; q16 += (size_t)BN * GD;
  u16* xoa_bf = q16; q16 += (size_t)M2 * GD;   // 59 MB

  k_setup<<<768, 256, 0, stream>>>(gvW1, gvW2, gvW3, guW1, guW2, guW3,
                                   umW1, umW2, umW3, aOW1, aIW1, aiW1, aSW1,
                                   E_u, E_i, nodes_u, nodes_i, u_users,
                                   gv1t, gv2t, gv3t, gu1t, gu2t, gu3t,
                                   um1t, um2t, um3t, aOt, aIt, ait,
                                   piWI, piWS, qjWi, poW);
  k_engine<<<512, 256, 0, stream>>>(E_i, E_r, E_u,
                                    uu_items, uu_items_r, u_items, u_items_r,
                                    i_users, i_users_r,
                                    gv1t, gv2t, gv3t, gu1t, gu2t, gu3t,
                                    gvb1, gvb2, gvb3, gub1, gub2, gub3,
                                    aOt, aIt, ait, aOb1, aIb1, aib1,
                                    aOW2, aIW2, aiW2, aOb2, aIb2, aib2,
                                    poW, piWI, qjWi,
                                    xoa_bf, xia_bf, fjt_bf, sOT, sIT, siT);
  k_stats<<<1020, 256, 0, stream>>>(sIT, siT, sOT, stats);
  k_agg<<<64 + BN / 8, 256, 0, stream>>>(xia_bf, fjt_bf, xoa_bf, sIT, siT, sOT, stats,
                                         linIW, linIb, ilinW, ilinb, linOW, linOb,
                                         aSW1, aSb1, aSW2, aSb2, piWS,
                                         hiI, zj, ho, sST);
  k_tail<<<GB / 64, 256, 0, stream>>>(hiI, zj, ho, sST, linOW, linOb,
                                      um1t, um2t, um3t, umb1, umb2, umb3,
                                      gW1, gb1, gW2, gb2, gW3, gb3, out);
}